// Round 5
// baseline (46.176 us; speedup 1.0000x reference)
//
#include <hip/hip_runtime.h>
#include <math.h>

#define D 2048
#define NROWS 16384
#define BLOCK 256
#define WPB   (BLOCK / 64)     // 4 waves per block
#define GRID  2048             // 8192 waves = max residency (256 CU x 32)
#define TOTW  (GRID * WPB)     // 8192
#define RPW   (NROWS / TOTW)   // 2 rows per wave

__global__ __launch_bounds__(BLOCK) void pal_row_theta(const float* __restrict__ recon,
                                                       const float* __restrict__ x,
                                                       float* __restrict__ blockPartial) {
    const int wave = threadIdx.x >> 6;
    const int lane = threadIdx.x & 63;
    const int gw   = blockIdx.x * WPB + wave;

    float wsum = 0.f;

#pragma unroll 1
    for (int r = 0; r < RPW; ++r) {
        const int row = gw + r * TOTW;
        const float4* a4 = reinterpret_cast<const float4*>(recon + (size_t)row * D);
        const float4* b4 = reinterpret_cast<const float4*>(x     + (size_t)row * D);

        float4 A[8], B[8];
        // Fence BEFORE the loads: compute from the previous iteration may not
        // sink into the load cluster, loads may not hoist above.
        __builtin_amdgcn_sched_barrier(0);
#pragma unroll
        for (int j = 0; j < 8; ++j) A[j] = a4[lane + 64 * j];
#pragma unroll
        for (int j = 0; j < 8; ++j) B[j] = b4[lane + 64 * j];
        // Fence AFTER the loads: FMAs may not be hoisted between the loads,
        // loads may not be sunk down to their first use. Forces all 16
        // global_load_dwordx4 to issue back-to-back -> 16 outstanding/lane.
        __builtin_amdgcn_sched_barrier(0);

        float dot = 0.f, rr = 0.f, xx = 0.f;
#pragma unroll
        for (int j = 0; j < 8; ++j) {
            dot += A[j].x * B[j].x + A[j].y * B[j].y + A[j].z * B[j].z + A[j].w * B[j].w;
            rr  += A[j].x * A[j].x + A[j].y * A[j].y + A[j].z * A[j].z + A[j].w * A[j].w;
            xx  += B[j].x * B[j].x + B[j].y * B[j].y + B[j].z * B[j].z + B[j].w * B[j].w;
        }

#pragma unroll
        for (int off = 32; off > 0; off >>= 1) {
            dot += __shfl_down(dot, off, 64);
            rr  += __shfl_down(rr,  off, 64);
            xx  += __shfl_down(xx,  off, 64);
        }

        if (lane == 0) {
            float c = dot / sqrtf(rr * xx);
            c = fminf(1.f, fmaxf(-1.f, c));
            wsum += acosf(c);
        }
    }

    __shared__ float sh[WPB];
    if (lane == 0) sh[wave] = wsum;
    __syncthreads();
    if (threadIdx.x == 0) {
        float s = 0.f;
#pragma unroll
        for (int w = 0; w < WPB; ++w) s += sh[w];
        blockPartial[blockIdx.x] = s;
    }
}

__global__ __launch_bounds__(256) void pal_mean(const float* __restrict__ blockPartial,
                                                float* __restrict__ out) {
    const float4* p4 = reinterpret_cast<const float4*>(blockPartial);  // 2048 floats
    float4 v0 = p4[threadIdx.x];
    float4 v1 = p4[threadIdx.x + 256];
    float s = v0.x + v0.y + v0.z + v0.w + v1.x + v1.y + v1.z + v1.w;
#pragma unroll
    for (int off = 32; off > 0; off >>= 1) s += __shfl_down(s, off, 64);
    __shared__ float sh[4];
    const int wave = threadIdx.x >> 6;
    const int lane = threadIdx.x & 63;
    if (lane == 0) sh[wave] = s;
    __syncthreads();
    if (threadIdx.x == 0) {
        out[0] = (sh[0] + sh[1] + sh[2] + sh[3]) / (float)NROWS;
    }
}

extern "C" void kernel_launch(void* const* d_in, const int* in_sizes, int n_in,
                              void* d_out, int out_size, void* d_ws, size_t ws_size,
                              hipStream_t stream) {
    const float* recon = (const float*)d_in[0];
    const float* x     = (const float*)d_in[1];
    float* out     = (float*)d_out;
    float* partial = (float*)d_ws;   // GRID floats = 8 KB scratch

    pal_row_theta<<<GRID, BLOCK, 0, stream>>>(recon, x, partial);
    pal_mean<<<1, 256, 0, stream>>>(partial, out);
}

// Round 6
// 46.091 us; speedup vs baseline: 1.0018x; 1.0018x over previous
//
#include <hip/hip_runtime.h>
#include <math.h>

#define D 2048
#define NROWS 16384
#define BLOCK 256
#define WPB   (BLOCK / 64)     // 4 waves per block
#define GRID  2048             // 8192 waves = max residency (256 CU x 32)
#define TOTW  (GRID * WPB)     // 8192
#define RPW   (NROWS / TOTW)   // 2 rows per wave
#define NT_START 13312         // rows >= this are non-temporal (3/16 of data, 50 MB)
                               // keeps 218 MB < 256 MB L3 resident across replays

using f32x4 = __attribute__((ext_vector_type(4))) float;

template <bool NT>
__device__ __forceinline__ void row_accum(const f32x4* __restrict__ a4,
                                          const f32x4* __restrict__ b4,
                                          int lane, float& dot, float& rr, float& xx) {
    f32x4 A[8], B[8];
#pragma unroll
    for (int j = 0; j < 8; ++j) {
        if (NT) {
            A[j] = __builtin_nontemporal_load(&a4[lane + 64 * j]);
            B[j] = __builtin_nontemporal_load(&b4[lane + 64 * j]);
        } else {
            A[j] = a4[lane + 64 * j];
            B[j] = b4[lane + 64 * j];
        }
    }
#pragma unroll
    for (int j = 0; j < 8; ++j) {
        dot += A[j].x * B[j].x + A[j].y * B[j].y + A[j].z * B[j].z + A[j].w * B[j].w;
        rr  += A[j].x * A[j].x + A[j].y * A[j].y + A[j].z * A[j].z + A[j].w * A[j].w;
        xx  += B[j].x * B[j].x + B[j].y * B[j].y + B[j].z * B[j].z + B[j].w * B[j].w;
    }
}

__global__ __launch_bounds__(BLOCK) void pal_row_theta(const float* __restrict__ recon,
                                                       const float* __restrict__ x,
                                                       float* __restrict__ blockPartial) {
    const int wave = threadIdx.x >> 6;
    const int lane = threadIdx.x & 63;
    const int gw   = blockIdx.x * WPB + wave;

    float wsum = 0.f;

#pragma unroll 1
    for (int r = 0; r < RPW; ++r) {
        const int row = gw + r * TOTW;
        const f32x4* a4 = reinterpret_cast<const f32x4*>(recon + (size_t)row * D);
        const f32x4* b4 = reinterpret_cast<const f32x4*>(x     + (size_t)row * D);

        float dot = 0.f, rr = 0.f, xx = 0.f;
        if (row < NT_START) {       // wave-uniform branch, no divergence
            row_accum<false>(a4, b4, lane, dot, rr, xx);
        } else {
            row_accum<true>(a4, b4, lane, dot, rr, xx);
        }

#pragma unroll
        for (int off = 32; off > 0; off >>= 1) {
            dot += __shfl_down(dot, off, 64);
            rr  += __shfl_down(rr,  off, 64);
            xx  += __shfl_down(xx,  off, 64);
        }

        if (lane == 0) {
            float c = dot / sqrtf(rr * xx);
            c = fminf(1.f, fmaxf(-1.f, c));
            wsum += acosf(c);
        }
    }

    __shared__ float sh[WPB];
    if (lane == 0) sh[wave] = wsum;
    __syncthreads();
    if (threadIdx.x == 0) {
        float s = 0.f;
#pragma unroll
        for (int w = 0; w < WPB; ++w) s += sh[w];
        blockPartial[blockIdx.x] = s;
    }
}

__global__ __launch_bounds__(256) void pal_mean(const float* __restrict__ blockPartial,
                                                float* __restrict__ out) {
    const float4* p4 = reinterpret_cast<const float4*>(blockPartial);  // 2048 floats
    float4 v0 = p4[threadIdx.x];
    float4 v1 = p4[threadIdx.x + 256];
    float s = v0.x + v0.y + v0.z + v0.w + v1.x + v1.y + v1.z + v1.w;
#pragma unroll
    for (int off = 32; off > 0; off >>= 1) s += __shfl_down(s, off, 64);
    __shared__ float sh[4];
    const int wave = threadIdx.x >> 6;
    const int lane = threadIdx.x & 63;
    if (lane == 0) sh[wave] = s;
    __syncthreads();
    if (threadIdx.x == 0) {
        out[0] = (sh[0] + sh[1] + sh[2] + sh[3]) / (float)NROWS;
    }
}

extern "C" void kernel_launch(void* const* d_in, const int* in_sizes, int n_in,
                              void* d_out, int out_size, void* d_ws, size_t ws_size,
                              hipStream_t stream) {
    const float* recon = (const float*)d_in[0];
    const float* x     = (const float*)d_in[1];
    float* out     = (float*)d_out;
    float* partial = (float*)d_ws;   // GRID floats = 8 KB scratch

    pal_row_theta<<<GRID, BLOCK, 0, stream>>>(recon, x, partial);
    pal_mean<<<1, 256, 0, stream>>>(partial, out);
}